// Round 1
// baseline (1918.402 us; speedup 1.0000x reference)
//
#include <hip/hip_runtime.h>
#include <hip/hip_bf16.h>

#define BB 64
#define TT 1536
#define FF 512
#define TP 256
#define UU 256
#define GG 1024
#define NC 250

__device__ __forceinline__ float hsig(float z) {
    return fminf(fmaxf(fmaf(z, 0.2f, 0.5f), 0.0f), 1.0f);
}

// ---------------------------------------------------------------------------
// Kernel 1: AveragePooling1D(6) over time.  x[64,1536,512] -> xp[64,256,512]
// One thread per output element; coalesced over f.
// ---------------------------------------------------------------------------
__global__ __launch_bounds__(256) void pool_kernel(const float* __restrict__ x,
                                                   float* __restrict__ xp) {
    int idx = blockIdx.x * 256 + threadIdx.x;   // [0, 16384*512)
    int f = idx & (FF - 1);
    int m = idx >> 9;                            // b*TP + tp
    int b = m >> 8;
    int tp = m & (TP - 1);
    const float* src = x + ((size_t)b * TT + (size_t)tp * 6) * FF + f;
    float s = 0.0f;
#pragma unroll
    for (int j = 0; j < 6; ++j) s += src[j * FF];
    xp[idx] = s * (1.0f / 6.0f);
}

// ---------------------------------------------------------------------------
// Kernel 2: zx = xp @ W + b.  [16384,512] @ [512,1024].  fp32 LDS-tiled GEMM,
// BM=BN=64, BK=16, 256 threads, 4x4 microtile per thread.
// ---------------------------------------------------------------------------
__global__ __launch_bounds__(256) void gemm_zx(const float* __restrict__ A,
                                               const float* __restrict__ Wm,
                                               const float* __restrict__ bias,
                                               float* __restrict__ C) {
    __shared__ float As[16][68];   // [k][m], padded to dodge store conflicts
    __shared__ float Bs[16][68];   // [k][n]
    const int tid = threadIdx.x;
    const int bn = blockIdx.x * 64;
    const int bm = blockIdx.y * 64;
    const int tx = tid & 15, ty = tid >> 4;
    const int lam = tid >> 2, lak = (tid & 3) * 4;   // A tile: row lam, k lak..lak+3
    const int lbk = tid >> 4, lbn = (tid & 15) * 4;  // B tile: k lbk, col lbn..lbn+3
    float acc[4][4] = {};

    for (int k0 = 0; k0 < FF; k0 += 16) {
        float4 av = *(const float4*)(A + (size_t)(bm + lam) * FF + k0 + lak);
        float4 bv = *(const float4*)(Wm + (size_t)(k0 + lbk) * GG + bn + lbn);
        __syncthreads();
        As[lak + 0][lam] = av.x;
        As[lak + 1][lam] = av.y;
        As[lak + 2][lam] = av.z;
        As[lak + 3][lam] = av.w;
        *(float4*)&Bs[lbk][lbn] = bv;
        __syncthreads();
#pragma unroll
        for (int kk = 0; kk < 16; ++kk) {
            float a[4], bb[4];
#pragma unroll
            for (int i = 0; i < 4; ++i) a[i] = As[kk][ty * 4 + i];
#pragma unroll
            for (int j = 0; j < 4; ++j) bb[j] = Bs[kk][tx * 4 + j];
#pragma unroll
            for (int i = 0; i < 4; ++i)
#pragma unroll
                for (int j = 0; j < 4; ++j)
                    acc[i][j] = fmaf(a[i], bb[j], acc[i][j]);
        }
    }
#pragma unroll
    for (int i = 0; i < 4; ++i) {
        int row = bm + ty * 4 + i;
#pragma unroll
        for (int j = 0; j < 4; ++j) {
            int col = bn + tx * 4 + j;
            C[(size_t)row * GG + col] = acc[i][j] + bias[col];
        }
    }
}

// ---------------------------------------------------------------------------
// Kernel 3: R fp32 -> bf16 (halves the scan's per-step L2 traffic).
// ---------------------------------------------------------------------------
__global__ __launch_bounds__(256) void conv_bf16(const float* __restrict__ R,
                                                 __hip_bfloat16* __restrict__ Rb) {
    int i = blockIdx.x * 256 + threadIdx.x;   // exactly 262144 threads
    Rb[i] = __float2bfloat16(R[i]);
}

// ---------------------------------------------------------------------------
// Kernel 4: LSTM scan. One workgroup per batch element (64 WGs, fully
// independent -> no inter-WG sync). 512 threads; thread t owns gate columns
// {2t, 2t+1}. h (256 fp32) lives in LDS; c lives in registers of threads<256.
// R is streamed bf16 from L2 every step (pairs packed in a dword per lane).
// ---------------------------------------------------------------------------
__global__ __launch_bounds__(512) void lstm_scan(const float* __restrict__ zx,
                                                 const unsigned int* __restrict__ Rp,
                                                 float* __restrict__ hfin) {
    __shared__ __align__(16) float h_lds[UU];
    __shared__ __align__(16) float z_lds[GG];
    const int b = blockIdx.x;
    const int tid = threadIdx.x;
    if (tid < UU) h_lds[tid] = 0.0f;
    float c = 0.0f;
    const float* zrow = zx + (size_t)b * TP * GG;
    __syncthreads();

    for (int t = 0; t < TP; ++t) {
        float2 z2 = *(const float2*)(zrow + (size_t)t * GG + tid * 2);
        float z0 = z2.x, z1 = z2.y;
        for (int u = 0; u < UU; u += 8) {
            float4 ha = *(const float4*)&h_lds[u];
            float4 hb = *(const float4*)&h_lds[u + 4];
            unsigned int r0 = Rp[(u + 0) * (GG / 2) + tid];
            unsigned int r1 = Rp[(u + 1) * (GG / 2) + tid];
            unsigned int r2 = Rp[(u + 2) * (GG / 2) + tid];
            unsigned int r3 = Rp[(u + 3) * (GG / 2) + tid];
            unsigned int r4 = Rp[(u + 4) * (GG / 2) + tid];
            unsigned int r5 = Rp[(u + 5) * (GG / 2) + tid];
            unsigned int r6 = Rp[(u + 6) * (GG / 2) + tid];
            unsigned int r7 = Rp[(u + 7) * (GG / 2) + tid];
            z0 = fmaf(__uint_as_float(r0 << 16), ha.x, z0);
            z1 = fmaf(__uint_as_float(r0 & 0xffff0000u), ha.x, z1);
            z0 = fmaf(__uint_as_float(r1 << 16), ha.y, z0);
            z1 = fmaf(__uint_as_float(r1 & 0xffff0000u), ha.y, z1);
            z0 = fmaf(__uint_as_float(r2 << 16), ha.z, z0);
            z1 = fmaf(__uint_as_float(r2 & 0xffff0000u), ha.z, z1);
            z0 = fmaf(__uint_as_float(r3 << 16), ha.w, z0);
            z1 = fmaf(__uint_as_float(r3 & 0xffff0000u), ha.w, z1);
            z0 = fmaf(__uint_as_float(r4 << 16), hb.x, z0);
            z1 = fmaf(__uint_as_float(r4 & 0xffff0000u), hb.x, z1);
            z0 = fmaf(__uint_as_float(r5 << 16), hb.y, z0);
            z1 = fmaf(__uint_as_float(r5 & 0xffff0000u), hb.y, z1);
            z0 = fmaf(__uint_as_float(r6 << 16), hb.z, z0);
            z1 = fmaf(__uint_as_float(r6 & 0xffff0000u), hb.z, z1);
            z0 = fmaf(__uint_as_float(r7 << 16), hb.w, z0);
            z1 = fmaf(__uint_as_float(r7 & 0xffff0000u), hb.w, z1);
        }
        *(float2*)&z_lds[tid * 2] = make_float2(z0, z1);
        __syncthreads();
        if (tid < UU) {
            float zi = z_lds[tid];
            float zf = z_lds[UU + tid];
            float zg = z_lds[2 * UU + tid];
            float zo = z_lds[3 * UU + tid];
            float ig = hsig(zi);
            float fg = hsig(zf);
            float gv = tanhf(zg);
            float og = hsig(zo);
            c = fmaf(fg, c, ig * gv);
            h_lds[tid] = og * tanhf(c);
        }
        __syncthreads();
    }
    if (tid < UU) hfin[(size_t)b * UU + tid] = h_lds[tid];
}

// ---------------------------------------------------------------------------
// Kernel 5: logits = h @ Wd + bd; softmax.  One WG per batch row.
// ---------------------------------------------------------------------------
__global__ __launch_bounds__(256) void dense_softmax(const float* __restrict__ hfin,
                                                     const float* __restrict__ Wd,
                                                     const float* __restrict__ bd,
                                                     float* __restrict__ out) {
    __shared__ __align__(16) float hbuf[UU];
    __shared__ float red[256];
    const int b = blockIdx.x;
    const int tid = threadIdx.x;
    hbuf[tid] = hfin[(size_t)b * UU + tid];
    __syncthreads();
    float logit = -3.0e38f;
    if (tid < NC) {
        float acc = bd[tid];
        for (int u = 0; u < UU; u += 4) {
            float4 hv = *(const float4*)&hbuf[u];
            acc = fmaf(hv.x, Wd[(size_t)(u + 0) * NC + tid], acc);
            acc = fmaf(hv.y, Wd[(size_t)(u + 1) * NC + tid], acc);
            acc = fmaf(hv.z, Wd[(size_t)(u + 2) * NC + tid], acc);
            acc = fmaf(hv.w, Wd[(size_t)(u + 3) * NC + tid], acc);
        }
        logit = acc;
    }
    red[tid] = logit;
    __syncthreads();
    for (int s = 128; s > 0; s >>= 1) {
        if (tid < s) red[tid] = fmaxf(red[tid], red[tid + s]);
        __syncthreads();
    }
    float mx = red[0];
    __syncthreads();
    float e = (tid < NC) ? expf(logit - mx) : 0.0f;
    red[tid] = e;
    __syncthreads();
    for (int s = 128; s > 0; s >>= 1) {
        if (tid < s) red[tid] += red[tid + s];
        __syncthreads();
    }
    if (tid < NC) out[(size_t)b * NC + tid] = e / red[0];
}

// ---------------------------------------------------------------------------
extern "C" void kernel_launch(void* const* d_in, const int* in_sizes, int n_in,
                              void* d_out, int out_size, void* d_ws, size_t ws_size,
                              hipStream_t stream) {
    const float* x  = (const float*)d_in[0];
    const float* W  = (const float*)d_in[1];
    const float* R  = (const float*)d_in[2];
    const float* bv = (const float*)d_in[3];
    const float* Wd = (const float*)d_in[4];
    const float* bd = (const float*)d_in[5];
    float* out = (float*)d_out;

    // workspace layout (~97 MiB)
    float* xp = (float*)d_ws;                                  // 16384*512 f32
    float* zx = xp + (size_t)16384 * 512;                      // 16384*1024 f32
    __hip_bfloat16* Rb = (__hip_bfloat16*)(zx + (size_t)16384 * 1024); // 262144 bf16
    float* hfin = (float*)((char*)Rb + (size_t)262144 * 2);    // 64*256 f32

    hipLaunchKernelGGL(pool_kernel, dim3(32768), dim3(256), 0, stream, x, xp);
    hipLaunchKernelGGL(conv_bf16, dim3(1024), dim3(256), 0, stream, R, Rb);
    hipLaunchKernelGGL(gemm_zx, dim3(16, 256), dim3(256), 0, stream, xp, W, bv, zx);
    hipLaunchKernelGGL(lstm_scan, dim3(64), dim3(512), 0, stream, zx,
                       (const unsigned int*)Rb, hfin);
    hipLaunchKernelGGL(dense_softmax, dim3(64), dim3(256), 0, stream, hfin, Wd, bd, out);
}

// Round 2
// 924.213 us; speedup vs baseline: 2.0757x; 2.0757x over previous
//
#include <hip/hip_runtime.h>
#include <hip/hip_bf16.h>

#define BB 64
#define TT 1536
#define FF 512
#define TP 256
#define UU 256
#define GG 1024
#define NC 250

typedef _Float16 h2_t __attribute__((ext_vector_type(2)));

#if defined(__has_builtin)
#  if __has_builtin(__builtin_amdgcn_fdot2)
#    define FDOT2(a, b, c) __builtin_amdgcn_fdot2((a), (b), (c), false)
#  endif
#endif
#ifndef FDOT2
__device__ __forceinline__ float fdot2_fb(h2_t a, h2_t b, float c) {
    return c + (float)a[0] * (float)b[0] + (float)a[1] * (float)b[1];
}
#  define FDOT2(a, b, c) fdot2_fb((a), (b), (c))
#endif

#define BC(u) __builtin_bit_cast(h2_t, (u))

__device__ __forceinline__ float hsig(float z) {
    return fminf(fmaxf(fmaf(z, 0.2f, 0.5f), 0.0f), 1.0f);
}

// overflow-safe fast tanh via exp2-based expf
__device__ __forceinline__ float ftanh(float x) {
    float ax = fabsf(x);
    float e = __expf(-2.0f * ax);            // in (0,1], never overflows
    float t = (1.0f - e) / (1.0f + e);
    return copysignf(t, x);
}

__device__ __forceinline__ void dot4(float& z, const uint4& r, const uint4& h) {
    z = FDOT2(BC(r.x), BC(h.x), z);
    z = FDOT2(BC(r.y), BC(h.y), z);
    z = FDOT2(BC(r.z), BC(h.z), z);
    z = FDOT2(BC(r.w), BC(h.w), z);
}

// ---------------------------------------------------------------------------
// Kernel 1: AveragePooling1D(6).  x[64,1536,512] -> xp[64,256,512]
// ---------------------------------------------------------------------------
__global__ __launch_bounds__(256) void pool_kernel(const float* __restrict__ x,
                                                   float* __restrict__ xp) {
    int idx = blockIdx.x * 256 + threadIdx.x;
    int f = idx & (FF - 1);
    int m = idx >> 9;
    int b = m >> 8;
    int tp = m & (TP - 1);
    const float* src = x + ((size_t)b * TT + (size_t)tp * 6) * FF + f;
    float s = 0.0f;
#pragma unroll
    for (int j = 0; j < 6; ++j) s += src[j * FF];
    xp[idx] = s * (1.0f / 6.0f);
}

// ---------------------------------------------------------------------------
// Kernel 2: zx = xp @ W + b.  fp32 LDS-tiled GEMM (unchanged this round).
// ---------------------------------------------------------------------------
__global__ __launch_bounds__(256) void gemm_zx(const float* __restrict__ A,
                                               const float* __restrict__ Wm,
                                               const float* __restrict__ bias,
                                               float* __restrict__ C) {
    __shared__ float As[16][68];
    __shared__ float Bs[16][68];
    const int tid = threadIdx.x;
    const int bn = blockIdx.x * 64;
    const int bm = blockIdx.y * 64;
    const int tx = tid & 15, ty = tid >> 4;
    const int lam = tid >> 2, lak = (tid & 3) * 4;
    const int lbk = tid >> 4, lbn = (tid & 15) * 4;
    float acc[4][4] = {};

    for (int k0 = 0; k0 < FF; k0 += 16) {
        float4 av = *(const float4*)(A + (size_t)(bm + lam) * FF + k0 + lak);
        float4 bv = *(const float4*)(Wm + (size_t)(k0 + lbk) * GG + bn + lbn);
        __syncthreads();
        As[lak + 0][lam] = av.x;
        As[lak + 1][lam] = av.y;
        As[lak + 2][lam] = av.z;
        As[lak + 3][lam] = av.w;
        *(float4*)&Bs[lbk][lbn] = bv;
        __syncthreads();
#pragma unroll
        for (int kk = 0; kk < 16; ++kk) {
            float a[4], bb[4];
#pragma unroll
            for (int i = 0; i < 4; ++i) a[i] = As[kk][ty * 4 + i];
#pragma unroll
            for (int j = 0; j < 4; ++j) bb[j] = Bs[kk][tx * 4 + j];
#pragma unroll
            for (int i = 0; i < 4; ++i)
#pragma unroll
                for (int j = 0; j < 4; ++j)
                    acc[i][j] = fmaf(a[i], bb[j], acc[i][j]);
        }
    }
#pragma unroll
    for (int i = 0; i < 4; ++i) {
        int row = bm + ty * 4 + i;
#pragma unroll
        for (int j = 0; j < 4; ++j) {
            int col = bn + tx * 4 + j;
            C[(size_t)row * GG + col] = acc[i][j] + bias[col];
        }
    }
}

// ---------------------------------------------------------------------------
// Kernel 3: R fp32 [256][1024] -> packed-f16 Rp4 layout.
// Flat dword d: k4 = d>>12, c = (d>>2)&1023, i = d&3; k = 4*k4+i;
// dword = pack(f16(R[2k][c]), f16(R[2k+1][c])).
// This makes uint4 Rp4[k4][c] hold u-pairs 8k4..8k4+7 for column c.
// ---------------------------------------------------------------------------
__global__ __launch_bounds__(256) void conv_f16(const float* __restrict__ R,
                                                unsigned* __restrict__ Rp) {
    int d = blockIdx.x * 256 + threadIdx.x;      // [0, 131072)
    int k4 = d >> 12;
    int c = (d >> 2) & 1023;
    int i = d & 3;
    int k = 4 * k4 + i;
    h2_t p;
    p[0] = (_Float16)R[(size_t)(2 * k) * GG + c];
    p[1] = (_Float16)R[(size_t)(2 * k + 1) * GG + c];
    Rp[d] = __builtin_bit_cast(unsigned, p);
}

// ---------------------------------------------------------------------------
// Kernel 4: LSTM scan. One WG (512 thr) per batch element. Thread t owns gate
// columns {t, 512+t}: t<256 -> (i_t, g_t); t=256+j -> (f_j, o_j).
// R (packed f16, 512 KB) is 3-tier resident:
//   col t        : 32 uint4 in VGPRs (r0)
//   col 512+t    : 12 uint4 in VGPRs (r1) + 7 uint4 in LDS (56 KB) +
//                  13 uint4 streamed from L2 per step (104 KB/step vs 512 before)
// h carried as packed f16 pairs in LDS; dot via v_dot2_f32_f16 (f32 accum).
// ---------------------------------------------------------------------------
__global__ __launch_bounds__(512, 2) void lstm_scan(const float* __restrict__ zx,
                                                    const uint4* __restrict__ Rp4,
                                                    float* __restrict__ hfin) {
    __shared__ uint4 Rl[7][512];                    // 57344 B
    __shared__ __align__(16) unsigned h2s[GG / 8];  // 128 dwords = 256 f16
    __shared__ float2 zfo[UU];                      // (f_j, o_j) exchange
    const int b = blockIdx.x;
    const int t = threadIdx.x;

    uint4 r0[32];
    uint4 r1[12];
#pragma unroll
    for (int q = 0; q < 32; ++q) r0[q] = Rp4[q * GG + t];
#pragma unroll
    for (int q = 0; q < 12; ++q) r1[q] = Rp4[q * GG + 512 + t];
#pragma unroll
    for (int q = 0; q < 7; ++q) Rl[q][t] = Rp4[(12 + q) * GG + 512 + t];
    if (t < 128) h2s[t] = 0u;
    float c = 0.0f;
    const float* zrow = zx + (size_t)b * TP * GG;
    const uint4* rs_base = Rp4 + 19 * GG + 512 + t;
    __syncthreads();

    for (int step = 0; step < TP; ++step) {
        const float* zr = zrow + (size_t)step * GG;
        float z0 = zr[t];
        float z1 = zr[512 + t];
        const uint4* h4 = (const uint4*)h2s;
#pragma unroll
        for (int q = 0; q < 12; ++q) {
            uint4 hh = h4[q];
            dot4(z0, r0[q], hh);
            dot4(z1, r1[q], hh);
        }
#pragma unroll
        for (int q = 12; q < 19; ++q) {
            uint4 hh = h4[q];
            uint4 rb = Rl[q - 12][t];
            dot4(z0, r0[q], hh);
            dot4(z1, rb, hh);
        }
#pragma unroll
        for (int q = 19; q < 32; ++q) {
            uint4 hh = h4[q];
            uint4 rb = rs_base[(q - 19) * GG];
            dot4(z0, r0[q], hh);
            dot4(z1, rb, hh);
        }
        if (t >= UU) zfo[t - UU] = make_float2(z0, z1);
        __syncthreads();
        if (t < UU) {
            float zi = z0, zg = z1;
            float zf = zfo[t].x, zo = zfo[t].y;
            float ig = hsig(zi);
            float fg = hsig(zf);
            float gv = ftanh(zg);
            float og = hsig(zo);
            c = fmaf(fg, c, ig * gv);
            float h = og * ftanh(c);
            ((_Float16*)h2s)[t] = (_Float16)h;
            if (step == TP - 1) hfin[(size_t)b * UU + t] = h;
        }
        __syncthreads();
    }
}

// ---------------------------------------------------------------------------
// Kernel 5: logits = h @ Wd + bd; softmax.  One WG per batch row.
// ---------------------------------------------------------------------------
__global__ __launch_bounds__(256) void dense_softmax(const float* __restrict__ hfin,
                                                     const float* __restrict__ Wd,
                                                     const float* __restrict__ bd,
                                                     float* __restrict__ out) {
    __shared__ __align__(16) float hbuf[UU];
    __shared__ float red[256];
    const int b = blockIdx.x;
    const int tid = threadIdx.x;
    hbuf[tid] = hfin[(size_t)b * UU + tid];
    __syncthreads();
    float logit = -3.0e38f;
    if (tid < NC) {
        float acc = bd[tid];
        for (int u = 0; u < UU; u += 4) {
            float4 hv = *(const float4*)&hbuf[u];
            acc = fmaf(hv.x, Wd[(size_t)(u + 0) * NC + tid], acc);
            acc = fmaf(hv.y, Wd[(size_t)(u + 1) * NC + tid], acc);
            acc = fmaf(hv.z, Wd[(size_t)(u + 2) * NC + tid], acc);
            acc = fmaf(hv.w, Wd[(size_t)(u + 3) * NC + tid], acc);
        }
        logit = acc;
    }
    red[tid] = logit;
    __syncthreads();
    for (int s = 128; s > 0; s >>= 1) {
        if (tid < s) red[tid] = fmaxf(red[tid], red[tid + s]);
        __syncthreads();
    }
    float mx = red[0];
    __syncthreads();
    float e = (tid < NC) ? expf(logit - mx) : 0.0f;
    red[tid] = e;
    __syncthreads();
    for (int s = 128; s > 0; s >>= 1) {
        if (tid < s) red[tid] += red[tid + s];
        __syncthreads();
    }
    if (tid < NC) out[(size_t)b * NC + tid] = e / red[0];
}

// ---------------------------------------------------------------------------
extern "C" void kernel_launch(void* const* d_in, const int* in_sizes, int n_in,
                              void* d_out, int out_size, void* d_ws, size_t ws_size,
                              hipStream_t stream) {
    const float* x  = (const float*)d_in[0];
    const float* W  = (const float*)d_in[1];
    const float* R  = (const float*)d_in[2];
    const float* bv = (const float*)d_in[3];
    const float* Wd = (const float*)d_in[4];
    const float* bd = (const float*)d_in[5];
    float* out = (float*)d_out;

    float* xp = (float*)d_ws;                                   // 32 MB
    float* zx = xp + (size_t)16384 * 512;                       // 64 MB
    unsigned* Rp = (unsigned*)(zx + (size_t)16384 * 1024);      // 512 KB
    float* hfin = (float*)(Rp + (size_t)131072);                // 64 KB

    hipLaunchKernelGGL(pool_kernel, dim3(32768), dim3(256), 0, stream, x, xp);
    hipLaunchKernelGGL(conv_f16, dim3(512), dim3(256), 0, stream, R, Rp);
    hipLaunchKernelGGL(gemm_zx, dim3(16, 256), dim3(256), 0, stream, xp, W, bv, zx);
    hipLaunchKernelGGL(lstm_scan, dim3(64), dim3(512), 0, stream, zx,
                       (const uint4*)Rp, hfin);
    hipLaunchKernelGGL(dense_softmax, dim3(64), dim3(256), 0, stream, hfin, Wd, bd, out);
}

// Round 3
// 765.467 us; speedup vs baseline: 2.5062x; 1.2074x over previous
//
#include <hip/hip_runtime.h>
#include <hip/hip_bf16.h>

#define BB 64
#define TT 1536
#define FF 512
#define TP 256
#define UU 256
#define GG 1024
#define NC 250

typedef _Float16 h2_t __attribute__((ext_vector_type(2)));
typedef _Float16 f16x8 __attribute__((ext_vector_type(8)));
typedef float f32x4 __attribute__((ext_vector_type(4)));

#if defined(__has_builtin)
#  if __has_builtin(__builtin_amdgcn_fdot2)
#    define FDOT2(a, b, c) __builtin_amdgcn_fdot2((a), (b), (c), false)
#  endif
#endif
#ifndef FDOT2
__device__ __forceinline__ float fdot2_fb(h2_t a, h2_t b, float c) {
    return c + (float)a[0] * (float)b[0] + (float)a[1] * (float)b[1];
}
#  define FDOT2(a, b, c) fdot2_fb((a), (b), (c))
#endif

#define BC(u) __builtin_bit_cast(h2_t, (u))

__device__ __forceinline__ float hsig(float z) {
    return fminf(fmaxf(fmaf(z, 0.2f, 0.5f), 0.0f), 1.0f);
}

__device__ __forceinline__ float ftanh(float x) {
    float ax = fabsf(x);
    float e = __expf(-2.0f * ax);
    float t = (1.0f - e) / (1.0f + e);
    return copysignf(t, x);
}

__device__ __forceinline__ void dot4(float& z, const uint4& r, const uint4& h) {
    z = FDOT2(BC(r.x), BC(h.x), z);
    z = FDOT2(BC(r.y), BC(h.y), z);
    z = FDOT2(BC(r.z), BC(h.z), z);
    z = FDOT2(BC(r.w), BC(h.w), z);
}

// quad all-reduce add via DPP quad_perm (VALU pipe, no LDS)
#if defined(__has_builtin) && __has_builtin(__builtin_amdgcn_mov_dpp)
template <int CTRL>
__device__ __forceinline__ float qperm(float v) {
    return __builtin_bit_cast(float,
        __builtin_amdgcn_mov_dpp(__builtin_bit_cast(int, v), CTRL, 0xf, 0xf, true));
}
#else
template <int CTRL>
__device__ __forceinline__ float qperm(float v) {
    return __shfl_xor(v, CTRL == 0xB1 ? 1 : 2, 64);
}
#endif

// ---------------------------------------------------------------------------
// Kernel 1: AveragePooling1D(6).  x[64,1536,512] f32 -> xph[64,256,512] f16
// ---------------------------------------------------------------------------
__global__ __launch_bounds__(256) void pool_kernel(const float* __restrict__ x,
                                                   _Float16* __restrict__ xph) {
    int idx = blockIdx.x * 256 + threadIdx.x;
    int f = idx & (FF - 1);
    int m = idx >> 9;
    int b = m >> 8;
    int tp = m & (TP - 1);
    const float* src = x + ((size_t)b * TT + (size_t)tp * 6) * FF + f;
    float s = 0.0f;
#pragma unroll
    for (int j = 0; j < 6; ++j) s += src[j * FF];
    xph[idx] = (_Float16)(s * (1.0f / 6.0f));
}

// ---------------------------------------------------------------------------
// Kernel 2a: W f32 [512,1024] -> Wt f16 [1024,512] (transposed for MFMA B-frags)
// ---------------------------------------------------------------------------
__global__ __launch_bounds__(256) void conv_wt(const float* __restrict__ W,
                                               _Float16* __restrict__ Wt) {
    int d = blockIdx.x * 256 + threadIdx.x;   // [0, 524288)
    int n = d >> 9;
    int k = d & 511;
    Wt[d] = (_Float16)W[(size_t)k * GG + n];
}

// ---------------------------------------------------------------------------
// Kernel 2b: R f32 [256,1024] -> Rq packed f16 quads, layout uint4 Rq[q][t]:
// t=4g+s (g: 8-col group, s: 64-K slice), q = c_local*8+p4;
// quad (q,t) dword i = pack(f16 R[64s+8p4+2i][8g+c_local], f16 R[..+1][..]).
// ---------------------------------------------------------------------------
__global__ __launch_bounds__(256) void conv_rq(const float* __restrict__ R,
                                               unsigned* __restrict__ Rq) {
    int d = blockIdx.x * 256 + threadIdx.x;   // dword index [0, 131072)
    int i = d & 3;
    int qt = d >> 2;
    int t = qt & 511;
    int q = qt >> 9;
    int g = t >> 2, s = t & 3;
    int c = 8 * g + (q >> 3);
    int p4 = q & 7;
    int k = 64 * s + 8 * p4 + 2 * i;
    h2_t p;
    p[0] = (_Float16)R[(size_t)k * GG + c];
    p[1] = (_Float16)R[(size_t)(k + 1) * GG + c];
    Rq[d] = __builtin_bit_cast(unsigned, p);
}

// ---------------------------------------------------------------------------
// Kernel 3: zx = xph @ W + b via f16 MFMA 16x16x32.  M=16384,N=1024,K=512.
// 128x128 tile, 4 waves, each wave 64x64 (4x4 MFMA tiles). f32 accum/out.
// ---------------------------------------------------------------------------
__global__ __launch_bounds__(256, 2) void gemm_zx_mfma(const _Float16* __restrict__ Ah,
                                                       const _Float16* __restrict__ Bt,
                                                       const float* __restrict__ bias,
                                                       float* __restrict__ C) {
    __shared__ _Float16 As[128 * 40];   // row stride 40 f16 (pad) = 80 B
    __shared__ _Float16 Bs[128 * 40];
    const int tid = threadIdx.x;
    const int bn = blockIdx.x * 128;
    const int bm = blockIdx.y * 128;
    const int wave = tid >> 6, lane = tid & 63;
    const int wm = (wave & 1) * 64, wn = (wave >> 1) * 64;
    const int l15 = lane & 15, q8 = (lane >> 4) * 8;
    const int srow = tid >> 1, shalf = tid & 1;

    f32x4 acc[4][4] = {};
    const uint4* ag = (const uint4*)(Ah + (size_t)(bm + srow) * FF);
    const uint4* bg = (const uint4*)(Bt + (size_t)(bn + srow) * FF);
    uint4* as_st = (uint4*)As + 5 * srow + 2 * shalf;
    uint4* bs_st = (uint4*)Bs + 5 * srow + 2 * shalf;

    for (int k0 = 0; k0 < FF; k0 += 32) {
        int qi = (k0 >> 3) + shalf * 2;
        uint4 a0 = ag[qi], a1 = ag[qi + 1];
        uint4 b0 = bg[qi], b1 = bg[qi + 1];
        __syncthreads();
        as_st[0] = a0; as_st[1] = a1;
        bs_st[0] = b0; bs_st[1] = b1;
        __syncthreads();
        f16x8 af[4], bf[4];
#pragma unroll
        for (int mt = 0; mt < 4; ++mt)
            af[mt] = *(const f16x8*)&As[(wm + 16 * mt + l15) * 40 + q8];
#pragma unroll
        for (int nt = 0; nt < 4; ++nt)
            bf[nt] = *(const f16x8*)&Bs[(wn + 16 * nt + l15) * 40 + q8];
#pragma unroll
        for (int mt = 0; mt < 4; ++mt)
#pragma unroll
            for (int nt = 0; nt < 4; ++nt)
                acc[mt][nt] = __builtin_amdgcn_mfma_f32_16x16x32_f16(af[mt], bf[nt],
                                                                    acc[mt][nt], 0, 0, 0);
    }
    const int rq = (lane >> 4) * 4;
#pragma unroll
    for (int nt = 0; nt < 4; ++nt) {
        int col = bn + wn + 16 * nt + l15;
        float bv = bias[col];
#pragma unroll
        for (int mt = 0; mt < 4; ++mt) {
#pragma unroll
            for (int r = 0; r < 4; ++r) {
                int row = bm + wm + 16 * mt + rq + r;
                C[(size_t)row * GG + col] = ((const float*)&acc[mt][nt])[r] + bv;
            }
        }
    }
}

// ---------------------------------------------------------------------------
// Kernel 4: LSTM scan. 64 WGs (one per batch), 512 threads.
// Thread t: g=t>>2 (cols 8g..8g+7), s=t&3 (K slice 64s..64s+63).
// R per thread = 64 uint4: rv[50] VGPR + Rl[6] LDS + 8 streamed from L2.
// Quad DPP butterfly reduces the 4 K-slices; gate phase on threads<256.
// ---------------------------------------------------------------------------
__global__ __launch_bounds__(512, 2) void lstm_scan(const float* __restrict__ zx,
                                                    const uint4* __restrict__ Rq4,
                                                    float* __restrict__ hfin) {
    __shared__ uint4 Rl[6][512];                     // 49152 B
    __shared__ float zfull[GG];                      // 4096 B
    __shared__ __align__(16) uint4 h2s[36];          // 4 slices * 9 uint4 (8 + pad)
    const int b = blockIdx.x;
    const int t = threadIdx.x;
    const int g = t >> 2, s = t & 3;

    uint4 rv[50];
#pragma unroll
    for (int q = 0; q < 50; ++q) rv[q] = Rq4[q * 512 + t];
#pragma unroll
    for (int j = 0; j < 6; ++j) Rl[j][t] = Rq4[(50 + j) * 512 + t];
    if (t < 144) ((unsigned*)h2s)[t] = 0u;
    float c = 0.0f;
    const float* zrow = zx + (size_t)b * TP * GG;
    const uint4* sRq = Rq4 + 56 * 512 + t;
    const uint4* h4 = h2s;
    __syncthreads();

    for (int step = 0; step < TP; ++step) {
        // prefetch streamed R (col 7) and this step's zx gate values
        uint4 st[8];
#pragma unroll
        for (int j = 0; j < 8; ++j) st[j] = sRq[j * 512];
        float zxi = 0.f, zxf = 0.f, zxg = 0.f, zxo = 0.f;
        if (t < UU) {
            const float* zr = zrow + (size_t)step * GG;
            zxi = zr[t]; zxf = zr[UU + t]; zxg = zr[2 * UU + t]; zxo = zr[3 * UU + t];
        }

        float z[8] = {};
#pragma unroll
        for (int p4 = 0; p4 < 8; ++p4) {
            uint4 hh = h4[9 * s + p4];
#pragma unroll
            for (int cc = 0; cc < 8; ++cc) {
                int q = cc * 8 + p4;
                if (q < 50)      dot4(z[cc], rv[q], hh);
                else if (q < 56) dot4(z[cc], Rl[q - 50][t], hh);
                else             dot4(z[cc], st[q - 56], hh);
            }
        }
        // quad butterfly all-reduce over K-slices (lanes 4g..4g+3)
#pragma unroll
        for (int cc = 0; cc < 8; ++cc) {
            z[cc] += qperm<0xB1>(z[cc]);   // xor 1
            z[cc] += qperm<0x4E>(z[cc]);   // xor 2
        }
        // lane s publishes cols 8g+2s, 8g+2s+1
        float w0 = s == 0 ? z[0] : s == 1 ? z[2] : s == 2 ? z[4] : z[6];
        float w1 = s == 0 ? z[1] : s == 1 ? z[3] : s == 2 ? z[5] : z[7];
        *(float2*)&zfull[8 * g + 2 * s] = make_float2(w0, w1);
        __syncthreads();
        if (t < UU) {
            float zi = zfull[t] + zxi;
            float zf = zfull[UU + t] + zxf;
            float zg = zfull[2 * UU + t] + zxg;
            float zo = zfull[3 * UU + t] + zxo;
            float ig = hsig(zi);
            float fg = hsig(zf);
            float gv = ftanh(zg);
            float og = hsig(zo);
            c = fmaf(fg, c, ig * gv);
            float h = og * ftanh(c);
            int s2 = t >> 6, pos = t & 63;
            ((_Float16*)h2s)[s2 * 72 + pos] = (_Float16)h;
            if (step == TP - 1) hfin[(size_t)b * UU + t] = h;
        }
        __syncthreads();
    }
}

// ---------------------------------------------------------------------------
// Kernel 5: logits = h @ Wd + bd; softmax.  One WG per batch row.
// ---------------------------------------------------------------------------
__global__ __launch_bounds__(256) void dense_softmax(const float* __restrict__ hfin,
                                                     const float* __restrict__ Wd,
                                                     const float* __restrict__ bd,
                                                     float* __restrict__ out) {
    __shared__ __align__(16) float hbuf[UU];
    __shared__ float red[256];
    const int b = blockIdx.x;
    const int tid = threadIdx.x;
    hbuf[tid] = hfin[(size_t)b * UU + tid];
    __syncthreads();
    float logit = -3.0e38f;
    if (tid < NC) {
        float acc = bd[tid];
        for (int u = 0; u < UU; u += 4) {
            float4 hv = *(const float4*)&hbuf[u];
            acc = fmaf(hv.x, Wd[(size_t)(u + 0) * NC + tid], acc);
            acc = fmaf(hv.y, Wd[(size_t)(u + 1) * NC + tid], acc);
            acc = fmaf(hv.z, Wd[(size_t)(u + 2) * NC + tid], acc);
            acc = fmaf(hv.w, Wd[(size_t)(u + 3) * NC + tid], acc);
        }
        logit = acc;
    }
    red[tid] = logit;
    __syncthreads();
    for (int s = 128; s > 0; s >>= 1) {
        if (tid < s) red[tid] = fmaxf(red[tid], red[tid + s]);
        __syncthreads();
    }
    float mx = red[0];
    __syncthreads();
    float e = (tid < NC) ? expf(logit - mx) : 0.0f;
    red[tid] = e;
    __syncthreads();
    for (int s = 128; s > 0; s >>= 1) {
        if (tid < s) red[tid] += red[tid + s];
        __syncthreads();
    }
    if (tid < NC) out[(size_t)b * NC + tid] = e / red[0];
}

// ---------------------------------------------------------------------------
extern "C" void kernel_launch(void* const* d_in, const int* in_sizes, int n_in,
                              void* d_out, int out_size, void* d_ws, size_t ws_size,
                              hipStream_t stream) {
    const float* x  = (const float*)d_in[0];
    const float* W  = (const float*)d_in[1];
    const float* R  = (const float*)d_in[2];
    const float* bv = (const float*)d_in[3];
    const float* Wd = (const float*)d_in[4];
    const float* bd = (const float*)d_in[5];
    float* out = (float*)d_out;

    char* ws = (char*)d_ws;
    _Float16* xph = (_Float16*)ws;                         // 16 MB
    float* zx = (float*)(ws + 16777216);                   // 64 MB
    _Float16* Wt = (_Float16*)(ws + 83886080);             // 1 MB
    unsigned* Rq = (unsigned*)(ws + 84934656);             // 512 KB
    float* hfin = (float*)(ws + 85458944);                 // 64 KB

    hipLaunchKernelGGL(pool_kernel, dim3(32768), dim3(256), 0, stream, x, xph);
    hipLaunchKernelGGL(conv_wt, dim3(2048), dim3(256), 0, stream, W, Wt);
    hipLaunchKernelGGL(conv_rq, dim3(512), dim3(256), 0, stream, R, Rq);
    hipLaunchKernelGGL(gemm_zx_mfma, dim3(8, 128), dim3(256), 0, stream,
                       xph, Wt, bv, zx);
    hipLaunchKernelGGL(lstm_scan, dim3(64), dim3(512), 0, stream, zx,
                       (const uint4*)Rq, hfin);
    hipLaunchKernelGGL(dense_softmax, dim3(64), dim3(256), 0, stream, hfin, Wd, bd, out);
}